// Round 1
// baseline (223.822 us; speedup 1.0000x reference)
//
#include <hip/hip_runtime.h>
#include <math.h>

#define NB 16
#define NC 80
#define HH 128
#define WW 128
#define NOBJ 100
#define HW (HH*WW)

// ws layout:
//   bytes [0,64): 5 double accumulators: 0=pos_loss 1=neg_loss 2=num_pos 3=w_sum 4=giou_loss
//   bytes [64, ...): NPAR float arrays of NB*NOBJ each (sorted per-object params)
enum { P_CX=0, P_CY, P_WR, P_HR, P_IVX, P_IVY, P_IVG, P_X1, P_Y1, P_X2, P_Y2, P_CLS, P_VAL, NPAR };

// ---------------- Kernel 1: per-image object prep (sort + params + gsum) ----------
__global__ void prep_kernel(const float* __restrict__ ann, float* __restrict__ par) {
    int b = blockIdx.x;
    int i = threadIdx.x;            // blockDim = 128
    __shared__ float skey[128];

    float x1=0.f, y1=0.f, x2=0.f, y2=0.f, clsv=-1.f;
    float key = INFINITY;           // key = -log_a; invalid -> +inf (stable, last)
    if (i < NOBJ) {
        const float* a = ann + ((size_t)b*NOBJ + i)*5;
        x1=a[0]; y1=a[1]; x2=a[2]; y2=a[3]; clsv=a[4];
        if (clsv >= 0.f) {
            float area = (y2 - y1 + 1.f) * (x2 - x1 + 1.f);
            key = -__logf(fmaxf(area, 1e-12f));
        }
    }
    skey[i] = key;
    __syncthreads();

    if (i < NOBJ) {
        // stable ascending rank of key (== jnp.argsort(-log_a))
        int r = 0;
        for (int j = 0; j < NOBJ; ++j) {
            float kj = skey[j];
            if (kj < key || (kj == key && j < i)) r++;
        }

        bool valid = (clsv >= 0.f);
        float cx = truncf((x1 + x2) * 0.125f);       // *0.5/DOWN, DOWN=4
        float cy = truncf((y1 + y2) * 0.125f);
        float fx1 = fminf(fmaxf(x1*0.25f, 0.f), WW - 1.f);
        float fx2 = fminf(fmaxf(x2*0.25f, 0.f), WW - 1.f);
        float fy1 = fminf(fmaxf(y1*0.25f, 0.f), HH - 1.f);
        float fy2 = fminf(fmaxf(y2*0.25f, 0.f), HH - 1.f);
        int hr = (int)((fy2 - fy1) * 0.5f * 0.54f);  // trunc toward zero, matches astype(int32)
        int wr = (int)((fx2 - fx1) * 0.5f * 0.54f);
        float sx = (float)(2*wr + 1) / 6.0f;
        float sy = (float)(2*hr + 1) / 6.0f;
        float ivx = 1.f / (2.f * sx * sx);
        float ivy = 1.f / (2.f * sy * sy);

        // separable gaussian sum: gsum = (sum_y gy) * (sum_x gx); gx carries valid mask
        int yc = (int)cy, xc = (int)cx;
        float sgy = 0.f;
        {
            int y0 = max(0, yc - hr), y1i = min(HH - 1, yc + hr);
            for (int y = y0; y <= y1i; ++y) {
                float dy = (float)y - cy;
                sgy += __expf(-(dy*dy) * ivy);
            }
        }
        float sgx = 0.f;
        if (valid) {
            int x0 = max(0, xc - wr), x1i = min(WW - 1, xc + wr);
            for (int x = x0; x <= x1i; ++x) {
                float dx = (float)x - cx;
                sgx += __expf(-(dx*dx) * ivx);
            }
        }
        float gsum = fmaxf(sgy * sgx, 1e-12f);
        float ivg = 1.f / gsum;
        int cls_i = min(max((int)clsv, 0), NC - 1);

        size_t S = (size_t)NB * NOBJ;
        size_t o = (size_t)b * NOBJ + (size_t)r;
        par[P_CX*S + o] = cx;
        par[P_CY*S + o] = cy;
        par[P_WR*S + o] = (float)wr;
        par[P_HR*S + o] = (float)hr;
        par[P_IVX*S + o] = ivx;
        par[P_IVY*S + o] = ivy;
        par[P_IVG*S + o] = ivg;
        par[P_X1*S + o] = x1;
        par[P_Y1*S + o] = y1;
        par[P_X2*S + o] = x2;
        par[P_Y2*S + o] = y2;
        par[P_CLS*S + o] = __int_as_float(cls_i);
        par[P_VAL*S + o] = valid ? 1.f : 0.f;
    }
}

// ---------------- Kernel 2: per-pixel fused focal + GIoU ----------
__global__ __launch_bounds__(256) void loss_kernel(
        const float* __restrict__ heat, const float* __restrict__ wh,
        const float* __restrict__ par, double* __restrict__ acc) {
    int b = blockIdx.y;
    int pix = blockIdx.x * 256 + threadIdx.x;
    int x = pix & (WW - 1), y = pix >> 7;
    float fx = (float)x, fy = (float)y;

    __shared__ float s[NPAR][NOBJ];
    {
        size_t S = (size_t)NB * NOBJ;
        for (int t = threadIdx.x; t < NPAR * NOBJ; t += 256) {
            int pidx = t / NOBJ, o = t - pidx * NOBJ;
            s[pidx][o] = par[(size_t)pidx * S + (size_t)b * NOBJ + o];
        }
    }
    __syncthreads();

    // ---- pass 1: owner = last (largest sorted idx) covering object ----
    int owner = -1; float gown = 0.f;
    for (int n = 0; n < NOBJ; ++n) {
        if (s[P_VAL][n] == 0.f) continue;
        float dx = fx - s[P_CX][n], dy = fy - s[P_CY][n];
        if (fabsf(dx) <= s[P_WR][n] && fabsf(dy) <= s[P_HR][n]) {
            owner = n;
            gown = __expf(-(dx*dx) * s[P_IVX][n]) * __expf(-(dy*dy) * s[P_IVY][n]);
        }
    }

    // ---- focal baseline: tgt = 0 for all 80 classes ----
    // pred = sigmoid(h); baseline = -log(1-pred)*pred^2 = (h + log(1+e^-h)) * p^2
    const float* hb = heat + (size_t)b * NC * HW + pix;
    float negl = 0.f, posl = 0.f, npos = 0.f;
    #pragma unroll 4
    for (int c = 0; c < NC; ++c) {
        float h = hb[(size_t)c * HW];
        float e = __expf(-h);
        float q = 1.f + e;
        float lq = __logf(q);
        float p = 1.f / q;
        negl += (h + lq) * p * p;
    }

    // ---- sparse corrections for classes with a covering object ----
    if (owner >= 0) {
        for (int i = 0; i < NOBJ; ++i) {
            float dxi = fx - s[P_CX][i], dyi = fy - s[P_CY][i];
            bool cov = (s[P_VAL][i] != 0.f) && fabsf(dxi) <= s[P_WR][i] && fabsf(dyi) <= s[P_HR][i];
            if (!cov) continue;
            int ci = __float_as_int(s[P_CLS][i]);
            // only first covering object of each class handles that class
            bool first = true;
            for (int j = 0; j < i; ++j) {
                if (__float_as_int(s[P_CLS][j]) != ci) continue;
                if (s[P_VAL][j] == 0.f) continue;
                float dxj = fx - s[P_CX][j], dyj = fy - s[P_CY][j];
                if (fabsf(dxj) <= s[P_WR][j] && fabsf(dyj) <= s[P_HR][j]) { first = false; break; }
            }
            if (!first) continue;
            float t = __expf(-(dxi*dxi) * s[P_IVX][i]) * __expf(-(dyi*dyi) * s[P_IVY][i]);
            for (int j = i + 1; j < NOBJ; ++j) {
                if (__float_as_int(s[P_CLS][j]) != ci) continue;
                if (s[P_VAL][j] == 0.f) continue;
                float dxj = fx - s[P_CX][j], dyj = fy - s[P_CY][j];
                if (fabsf(dxj) <= s[P_WR][j] && fabsf(dyj) <= s[P_HR][j]) {
                    float gj = __expf(-(dxj*dxj) * s[P_IVX][j]) * __expf(-(dyj*dyj) * s[P_IVY][j]);
                    t = fmaxf(t, gj);
                }
            }
            float h = hb[(size_t)ci * HW];
            float e = __expf(-h);
            float q = 1.f + e;
            float lq = __logf(q);
            float p = 1.f / q;
            float basef = (h + lq) * p * p;     // what the baseline loop added for this class
            if (t == 1.0f) {
                posl += lq * (1.f - p) * (1.f - p);   // -log(p)*(1-p)^2
                negl -= basef;                        // pos pixel excluded from neg
                npos += 1.f;
            } else {
                float u1 = 1.f - t;
                float u2 = u1 * u1;
                negl += basef * (u2 * u2 - 1.f);      // weight (1-t)^4 instead of 1
            }
        }
    }

    // ---- GIoU on covered pixels ----
    float wsum = 0.f, gl = 0.f;
    if (owner >= 0) {
        float w = gown * s[P_IVG][owner];
        const float* whb = wh + (size_t)b * 4 * HW + pix;
        float w0 = whb[0], w1 = whb[HW], w2 = whb[2*HW], w3 = whb[3*HW];
        float bx = fx * 4.f, by = fy * 4.f;
        float px1 = bx - w0, py1 = by - w1, px2 = bx + w2, py2 = by + w3;
        float tx1 = s[P_X1][owner], ty1 = s[P_Y1][owner];
        float tx2 = s[P_X2][owner], ty2 = s[P_Y2][owner];
        float ltx = fmaxf(px1, tx1), lty = fmaxf(py1, ty1);
        float rbx = fminf(px2, tx2), rby = fminf(py2, ty2);
        float iw = fmaxf(rbx - ltx + 1.f, 0.f), ih = fmaxf(rby - lty + 1.f, 0.f);
        float e1x = fminf(px1, tx1), e1y = fminf(py1, ty1);
        float e2x = fmaxf(px2, tx2), e2y = fmaxf(py2, ty2);
        float ew = fmaxf(e2x - e1x + 1.f, 0.f), eh = fmaxf(e2y - e1y + 1.f, 0.f);
        float ov = iw * ih;
        float ap = (px2 - px1 + 1.f) * (py2 - py1 + 1.f);
        float ag = (tx2 - tx1 + 1.f) * (ty2 - ty1 + 1.f);
        float u = ap + ag - ov;
        float iou = ov / u;
        float ea = ew * eh;
        float giou = iou - (ea - u) / ea;
        wsum = w;
        gl = (1.f - giou) * w;
    }

    // ---- block reduction -> global double atomics ----
    float vals[5] = { posl, negl, npos, wsum, gl };
    #pragma unroll
    for (int k = 0; k < 5; ++k) {
        float v = vals[k];
        for (int off = 32; off > 0; off >>= 1) v += __shfl_down(v, off, 64);
        vals[k] = v;
    }
    __shared__ float red[5][4];
    int lane = threadIdx.x & 63, wv = threadIdx.x >> 6;
    if (lane == 0) {
        #pragma unroll
        for (int k = 0; k < 5; ++k) red[k][wv] = vals[k];
    }
    __syncthreads();
    if (threadIdx.x == 0) {
        #pragma unroll
        for (int k = 0; k < 5; ++k) {
            double vsum = (double)red[k][0] + (double)red[k][1] + (double)red[k][2] + (double)red[k][3];
            atomicAdd(&acc[k], vsum);
        }
    }
}

// ---------------- Kernel 3: finalize ----------
__global__ void finalize_kernel(const double* __restrict__ acc, float* __restrict__ out) {
    double hm = (acc[2] > 0.0) ? (acc[0] + acc[1]) / acc[2] : acc[1];
    out[0] = (float)hm;                                   // HM_W = 1.0
    out[1] = (float)(acc[4] / (acc[3] + 1e-4) * 0.1);     // WH_W = 0.1
}

extern "C" void kernel_launch(void* const* d_in, const int* in_sizes, int n_in,
                              void* d_out, int out_size, void* d_ws, size_t ws_size,
                              hipStream_t stream) {
    const float* heat = (const float*)d_in[0];   // (16,80,128,128)
    const float* wh   = (const float*)d_in[1];   // (16,4,128,128)
    const float* ann  = (const float*)d_in[2];   // (16,100,5)
    float* out = (float*)d_out;                  // [hm_loss, wh_loss]

    double* acc = (double*)d_ws;
    float*  par = (float*)((char*)d_ws + 64);

    hipMemsetAsync(d_ws, 0, 64, stream);
    prep_kernel<<<NB, 128, 0, stream>>>(ann, par);
    dim3 grid(HW / 256, NB);
    loss_kernel<<<grid, 256, 0, stream>>>(heat, wh, par, acc);
    finalize_kernel<<<1, 1, 0, stream>>>(acc, out);
}

// Round 2
// 201.655 us; speedup vs baseline: 1.1099x; 1.1099x over previous
//
#include <hip/hip_runtime.h>
#include <math.h>

#define NB 16
#define NC 80
#define HH 128
#define WW 128
#define NOBJ 100
#define HW (HH*WW)
#define CHUNKS 8

// LDS param table indices
enum { P_CX=0, P_CY, P_WR, P_HR, P_IVX, P_IVY, P_IVG, P_X1, P_Y1, P_X2, P_Y2, P_CLS, P_VAL, NPAR };

// ws layout (doubles):
//  [0]=posl [1]=negl_corr [2]=npos [3]=wsum [4]=giou_loss
//  [5..5+NB) = dense negl partial per image
#define ACC_N (5 + NB)

// ---------------- Dense kernel: focal baseline with tgt=0, pure streaming ----------
// grid (16, 5, NB), block 256; thread handles 4 consecutive px x 16 classes.
__global__ __launch_bounds__(256) void focal_dense(const float* __restrict__ heat,
                                                   double* __restrict__ acc) {
    int b = blockIdx.z;
    int c0 = blockIdx.y * 16;
    int pix4 = (blockIdx.x * 256 + threadIdx.x) * 4;
    const float* base = heat + ((size_t)b * NC + c0) * HW + pix4;

    float negl = 0.f;
    #pragma unroll
    for (int c = 0; c < 16; ++c) {
        float4 v = *(const float4*)(base + (size_t)c * HW);
        float hv[4] = { v.x, v.y, v.z, v.w };
        #pragma unroll
        for (int k = 0; k < 4; ++k) {
            float h = hv[k];
            float e = __expf(-h);
            float q = 1.f + e;
            float lq = __logf(q);
            float p = 1.f / q;
            negl += (h + lq) * p * p;   // -log(1-pred) * pred^2, tgt=0
        }
    }
    // block reduce -> one double atomic into per-image slot
    float v = negl;
    for (int off = 32; off > 0; off >>= 1) v += __shfl_down(v, off, 64);
    __shared__ float red[4];
    int lane = threadIdx.x & 63, wv = threadIdx.x >> 6;
    if (lane == 0) red[wv] = v;
    __syncthreads();
    if (threadIdx.x == 0) {
        double s = (double)red[0] + (double)red[1] + (double)red[2] + (double)red[3];
        atomicAdd(&acc[5 + b], s);
    }
}

// ---------------- Scatter kernel: all sparse work over object windows ----------
// grid (NB, CHUNKS), block 128. Each block rebuilds the sorted param table in LDS,
// then processes objects i == blockIdx.y (mod CHUNKS).
__global__ __launch_bounds__(128) void scatter_kernel(const float* __restrict__ ann,
                                                      const float* __restrict__ heat,
                                                      const float* __restrict__ wh,
                                                      double* __restrict__ acc) {
    int b = blockIdx.x;
    int i0 = threadIdx.x;
    __shared__ float s[NPAR][NOBJ];
    __shared__ float skey[128];
    __shared__ int s_nv;
    if (i0 == 0) s_nv = 0;

    // ---- phase A: sort + per-object params (replicates reference _single_targets prep)
    float x1=0.f, y1=0.f, x2=0.f, y2=0.f, clsv=-1.f;
    float key = INFINITY;
    if (i0 < NOBJ) {
        const float* a = ann + ((size_t)b * NOBJ + i0) * 5;
        x1=a[0]; y1=a[1]; x2=a[2]; y2=a[3]; clsv=a[4];
        if (clsv >= 0.f) {
            float area = (y2 - y1 + 1.f) * (x2 - x1 + 1.f);
            key = -__logf(fmaxf(area, 1e-12f));
        }
    }
    skey[i0] = key;
    __syncthreads();

    if (i0 < NOBJ) {
        int r = 0;
        for (int j = 0; j < NOBJ; ++j) {
            float kj = skey[j];
            if (kj < key || (kj == key && j < i0)) r++;
        }
        bool valid = (clsv >= 0.f);
        if (valid) atomicAdd(&s_nv, 1);

        float cx = truncf((x1 + x2) * 0.125f);
        float cy = truncf((y1 + y2) * 0.125f);
        float fx1 = fminf(fmaxf(x1*0.25f, 0.f), WW - 1.f);
        float fx2 = fminf(fmaxf(x2*0.25f, 0.f), WW - 1.f);
        float fy1 = fminf(fmaxf(y1*0.25f, 0.f), HH - 1.f);
        float fy2 = fminf(fmaxf(y2*0.25f, 0.f), HH - 1.f);
        int hr = (int)((fy2 - fy1) * 0.5f * 0.54f);
        int wr = (int)((fx2 - fx1) * 0.5f * 0.54f);
        float sx = (float)(2*wr + 1) / 6.0f;
        float sy = (float)(2*hr + 1) / 6.0f;
        float ivx = 1.f / (2.f * sx * sx);
        float ivy = 1.f / (2.f * sy * sy);

        int yc = (int)cy, xc = (int)cx;
        float sgy = 0.f;
        {
            int ya = max(0, yc - hr), yb = min(HH - 1, yc + hr);
            for (int y = ya; y <= yb; ++y) {
                float dy = (float)y - cy;
                sgy += __expf(-(dy*dy) * ivy);
            }
        }
        float sgx = 0.f;
        if (valid) {
            int xa = max(0, xc - wr), xb = min(WW - 1, xc + wr);
            for (int x = xa; x <= xb; ++x) {
                float dx = (float)x - cx;
                sgx += __expf(-(dx*dx) * ivx);
            }
        }
        float gsum = fmaxf(sgy * sgx, 1e-12f);
        int cls_i = min(max((int)clsv, 0), NC - 1);

        s[P_CX][r] = cx;  s[P_CY][r] = cy;
        s[P_WR][r] = (float)wr;  s[P_HR][r] = (float)hr;
        s[P_IVX][r] = ivx;  s[P_IVY][r] = ivy;
        s[P_IVG][r] = 1.f / gsum;
        s[P_X1][r] = x1;  s[P_Y1][r] = y1;  s[P_X2][r] = x2;  s[P_Y2][r] = y2;
        s[P_CLS][r] = __int_as_float(cls_i);
        s[P_VAL][r] = valid ? 1.f : 0.f;
    }
    __syncthreads();
    int nv = s_nv;   // valid objects occupy sorted ranks [0, nv)

    float posl = 0.f, negl = 0.f, npos = 0.f, wsum = 0.f, gl = 0.f;

    // ---- phase B: walk windows of my chunk's objects
    for (int i = blockIdx.y; i < nv; i += CHUNKS) {
        float cx = s[P_CX][i], cy = s[P_CY][i];
        int wr = (int)s[P_WR][i], hr = (int)s[P_HR][i];
        int ci = __float_as_int(s[P_CLS][i]);
        float ivx = s[P_IVX][i], ivy = s[P_IVY][i];
        int xc = (int)cx, yc = (int)cy;
        int xa = max(0, xc - wr), xb = min(WW - 1, xc + wr);
        int ya = max(0, yc - hr), yb = min(HH - 1, yc + hr);
        int wN = xb - xa + 1, hN = yb - ya + 1, npix = wN * hN;

        for (int t0 = threadIdx.x; t0 < npix; t0 += 128) {
            int ry = t0 / wN;
            int px = xa + (t0 - ry * wN);
            int py = ya + ry;
            float fx = (float)px, fy = (float)py;

            // is object i the first (smallest sorted idx) covering object of class ci?
            bool first = true;
            for (int j = 0; j < i; ++j) {
                if (__float_as_int(s[P_CLS][j]) != ci) continue;
                float dxj = fx - s[P_CX][j], dyj = fy - s[P_CY][j];
                if (fabsf(dxj) <= s[P_WR][j] && fabsf(dyj) <= s[P_HR][j]) { first = false; break; }
            }

            float dxi = fx - cx, dyi = fy - cy;
            float gi = __expf(-(dxi*dxi) * ivx) * __expf(-(dyi*dyi) * ivy);
            float t = gi;
            bool is_owner = true;   // owner = largest covering sorted idx
            for (int j = i + 1; j < nv; ++j) {
                float dxj = fx - s[P_CX][j], dyj = fy - s[P_CY][j];
                if (fabsf(dxj) <= s[P_WR][j] && fabsf(dyj) <= s[P_HR][j]) {
                    is_owner = false;
                    if (first && __float_as_int(s[P_CLS][j]) == ci) {
                        float gj = __expf(-(dxj*dxj) * s[P_IVX][j]) * __expf(-(dyj*dyj) * s[P_IVY][j]);
                        t = fmaxf(t, gj);
                    }
                }
            }

            if (first) {
                // correction vs. the tgt=0 baseline the dense kernel added
                float h = heat[((size_t)b * NC + ci) * HW + (size_t)py * WW + px];
                float e = __expf(-h);
                float q = 1.f + e;
                float lq = __logf(q);
                float p = 1.f / q;
                float basef = (h + lq) * p * p;
                if (t == 1.0f) {
                    posl += lq * (1.f - p) * (1.f - p);  // -log(pred)*(1-pred)^2
                    negl -= basef;
                    npos += 1.f;
                } else {
                    float u1 = 1.f - t;
                    float u2 = u1 * u1;
                    negl += basef * (u2 * u2 - 1.f);     // (1-t)^4 weight instead of 1
                }
            }

            if (is_owner) {
                float w = gi * s[P_IVG][i];
                size_t po = (size_t)py * WW + px;
                const float* whb = wh + (size_t)b * 4 * HW + po;
                float w0 = whb[0], w1 = whb[HW], w2 = whb[2*HW], w3 = whb[3*HW];
                float bx = fx * 4.f, by = fy * 4.f;
                float px1 = bx - w0, py1 = by - w1, px2 = bx + w2, py2 = by + w3;
                float tx1 = s[P_X1][i], ty1 = s[P_Y1][i];
                float tx2 = s[P_X2][i], ty2 = s[P_Y2][i];
                float ltx = fmaxf(px1, tx1), lty = fmaxf(py1, ty1);
                float rbx = fminf(px2, tx2), rby = fminf(py2, ty2);
                float iw = fmaxf(rbx - ltx + 1.f, 0.f), ih = fmaxf(rby - lty + 1.f, 0.f);
                float e1x = fminf(px1, tx1), e1y = fminf(py1, ty1);
                float e2x = fmaxf(px2, tx2), e2y = fmaxf(py2, ty2);
                float ew = fmaxf(e2x - e1x + 1.f, 0.f), eh = fmaxf(e2y - e1y + 1.f, 0.f);
                float ov = iw * ih;
                float ap = (px2 - px1 + 1.f) * (py2 - py1 + 1.f);
                float ag = (tx2 - tx1 + 1.f) * (ty2 - ty1 + 1.f);
                float u = ap + ag - ov;
                float iou = ov / u;
                float ea = ew * eh;
                float giou = iou - (ea - u) / ea;
                wsum += w;
                gl += (1.f - giou) * w;
            }
        }
    }

    // ---- reduce 5 values over 2 waves -> 5 atomics
    float vals[5] = { posl, negl, npos, wsum, gl };
    #pragma unroll
    for (int k = 0; k < 5; ++k) {
        float v = vals[k];
        for (int off = 32; off > 0; off >>= 1) v += __shfl_down(v, off, 64);
        vals[k] = v;
    }
    __shared__ float red[5][2];
    int lane = threadIdx.x & 63, wv = threadIdx.x >> 6;
    if (lane == 0) {
        #pragma unroll
        for (int k = 0; k < 5; ++k) red[k][wv] = vals[k];
    }
    __syncthreads();
    if (threadIdx.x == 0) {
        #pragma unroll
        for (int k = 0; k < 5; ++k)
            atomicAdd(&acc[k], (double)red[k][0] + (double)red[k][1]);
    }
}

// ---------------- finalize ----------
__global__ void finalize_kernel(const double* __restrict__ acc, float* __restrict__ out) {
    double negl = acc[1];
    for (int b = 0; b < NB; ++b) negl += acc[5 + b];
    double hm = (acc[2] > 0.0) ? (acc[0] + negl) / acc[2] : negl;
    out[0] = (float)hm;                                   // HM_W = 1.0
    out[1] = (float)(acc[4] / (acc[3] + 1e-4) * 0.1);     // WH_W = 0.1
}

extern "C" void kernel_launch(void* const* d_in, const int* in_sizes, int n_in,
                              void* d_out, int out_size, void* d_ws, size_t ws_size,
                              hipStream_t stream) {
    const float* heat = (const float*)d_in[0];   // (16,80,128,128)
    const float* wh   = (const float*)d_in[1];   // (16,4,128,128)
    const float* ann  = (const float*)d_in[2];   // (16,100,5)
    float* out = (float*)d_out;

    double* acc = (double*)d_ws;
    hipMemsetAsync(d_ws, 0, ACC_N * sizeof(double), stream);

    scatter_kernel<<<dim3(NB, CHUNKS), 128, 0, stream>>>(ann, heat, wh, acc);
    focal_dense<<<dim3(16, 5, NB), 256, 0, stream>>>(heat, acc);
    finalize_kernel<<<1, 1, 0, stream>>>(acc, out);
}

// Round 3
// 146.336 us; speedup vs baseline: 1.5295x; 1.3780x over previous
//
#include <hip/hip_runtime.h>
#include <math.h>

#define NB 16
#define NC 80
#define HH 128
#define WW 128
#define NOBJ 100
#define HW (HH*WW)
#define DENSE_BLOCKS 1280            // NB*NC*HW/4 float4s / (256 thr * 16 f4/thr)
#define TOTAL_BLOCKS (DENSE_BLOCKS + NB*NOBJ)

// sorted param table indices
enum { P_CX=0, P_CY, P_WR, P_HR, P_IVX, P_IVY, P_IVG, P_X1, P_Y1, P_X2, P_Y2, P_CLS, NPAR };

// ws layout:
//  [0, 768):    double acc[96] = k*16+b, k: 0=posl 1=negl_corr 2=npos 3=wsum 4=giou; [80+b]=dense negl
//  [768, 832):  int nv[NB]
//  [832, ...):  float par[NPAR][NB][NOBJ]
#define ACC_DOUBLES 96
#define NV_OFF 768
#define PAR_OFF 832

// ---------------- Kernel 1: per-image prep (sort + params + gsum) + zero accumulators ----------
__global__ __launch_bounds__(128) void prep_kernel(const float* __restrict__ ann,
                                                   double* __restrict__ acc,
                                                   int* __restrict__ nv,
                                                   float* __restrict__ par) {
    int b = blockIdx.x;
    int i = threadIdx.x;
    __shared__ float skey[128];
    __shared__ int s_nv;
    if (i == 0) s_nv = 0;

    // zero the 6 accumulator slots owned by this image
    if (i < 5) acc[i * 16 + b] = 0.0;
    if (i == 5) acc[80 + b] = 0.0;

    float x1=0.f, y1=0.f, x2=0.f, y2=0.f, clsv=-1.f;
    float key = INFINITY;            // key = -log_a; invalid -> +inf (sorted last, stable)
    if (i < NOBJ) {
        const float* a = ann + ((size_t)b * NOBJ + i) * 5;
        x1=a[0]; y1=a[1]; x2=a[2]; y2=a[3]; clsv=a[4];
        if (clsv >= 0.f) {
            float area = (y2 - y1 + 1.f) * (x2 - x1 + 1.f);
            key = -__logf(fmaxf(area, 1e-12f));
        }
    }
    skey[i] = key;
    __syncthreads();

    if (i < NOBJ) {
        // stable ascending rank == jnp.argsort(-log_a)
        int r = 0;
        for (int j = 0; j < NOBJ; ++j) {
            float kj = skey[j];
            if (kj < key || (kj == key && j < i)) r++;
        }
        bool valid = (clsv >= 0.f);
        if (valid) atomicAdd(&s_nv, 1);

        float cx = truncf((x1 + x2) * 0.125f);       // *0.5/DOWN, DOWN=4
        float cy = truncf((y1 + y2) * 0.125f);
        float fx1 = fminf(fmaxf(x1*0.25f, 0.f), WW - 1.f);
        float fx2 = fminf(fmaxf(x2*0.25f, 0.f), WW - 1.f);
        float fy1 = fminf(fmaxf(y1*0.25f, 0.f), HH - 1.f);
        float fy2 = fminf(fmaxf(y2*0.25f, 0.f), HH - 1.f);
        int hr = (int)((fy2 - fy1) * 0.5f * 0.54f);  // trunc matches astype(int32)
        int wr = (int)((fx2 - fx1) * 0.5f * 0.54f);
        float sx = (float)(2*wr + 1) / 6.0f;
        float sy = (float)(2*hr + 1) / 6.0f;
        float ivx = 1.f / (2.f * sx * sx);
        float ivy = 1.f / (2.f * sy * sy);

        // separable gaussian sum (gx carries valid mask in reference)
        int yc = (int)cy, xc = (int)cx;
        float sgy = 0.f;
        {
            int ya = max(0, yc - hr), yb = min(HH - 1, yc + hr);
            for (int y = ya; y <= yb; ++y) {
                float dy = (float)y - cy;
                sgy += __expf(-(dy*dy) * ivy);
            }
        }
        float sgx = 0.f;
        if (valid) {
            int xa = max(0, xc - wr), xb = min(WW - 1, xc + wr);
            for (int x = xa; x <= xb; ++x) {
                float dx = (float)x - cx;
                sgx += __expf(-(dx*dx) * ivx);
            }
        }
        float gsum = fmaxf(sgy * sgx, 1e-12f);
        int cls_i = min(max((int)clsv, 0), NC - 1);

        size_t o = (size_t)b * NOBJ + (size_t)r;
        size_t S = (size_t)NB * NOBJ;
        par[P_CX*S + o]  = cx;
        par[P_CY*S + o]  = cy;
        par[P_WR*S + o]  = (float)wr;
        par[P_HR*S + o]  = (float)hr;
        par[P_IVX*S + o] = ivx;
        par[P_IVY*S + o] = ivy;
        par[P_IVG*S + o] = 1.f / gsum;
        par[P_X1*S + o]  = x1;
        par[P_Y1*S + o]  = y1;
        par[P_X2*S + o]  = x2;
        par[P_Y2*S + o]  = y2;
        par[P_CLS*S + o] = __int_as_float(cls_i);
    }
    __syncthreads();
    if (i == 0) nv[b] = s_nv;
}

// ---------------- Kernel 2: fused dense focal baseline + sparse corrections + GIoU ----------
__global__ __launch_bounds__(256) void main_kernel(const float* __restrict__ heat,
                                                   const float* __restrict__ wh,
                                                   const float* __restrict__ par,
                                                   const int* __restrict__ nv,
                                                   double* __restrict__ acc) {
    if (blockIdx.x < DENSE_BLOCKS) {
        // ===== dense path: flat streaming focal baseline (tgt = 0) =====
        const float4* hp = (const float4*)heat;
        size_t base = (size_t)blockIdx.x * 4096 + threadIdx.x;
        float4 v[16];
        #pragma unroll
        for (int k = 0; k < 16; ++k) v[k] = hp[base + (size_t)k * 256];
        float negl = 0.f;
        #pragma unroll
        for (int k = 0; k < 16; ++k) {
            float hv[4] = { v[k].x, v[k].y, v[k].z, v[k].w };
            #pragma unroll
            for (int m = 0; m < 4; ++m) {
                float h = hv[m];
                float e = __expf(-h);
                float q = 1.f + e;
                float lq = __logf(q);
                float p = 1.f / q;
                negl += (h + lq) * p * p;   // -log(1-pred) * pred^2
            }
        }
        float r = negl;
        for (int off = 32; off > 0; off >>= 1) r += __shfl_down(r, off, 64);
        __shared__ float dred[4];
        int lane = threadIdx.x & 63, wv = threadIdx.x >> 6;
        if (lane == 0) dred[wv] = r;
        __syncthreads();
        if (threadIdx.x == 0) {
            double s = (double)dred[0] + (double)dred[1] + (double)dred[2] + (double)dred[3];
            atomicAdd(&acc[80 + (blockIdx.x & 15)], s);
        }
        return;
    }

    // ===== scatter path: one block per (image, sorted object) =====
    int s = blockIdx.x - DENSE_BLOCKS;
    int b = s / NOBJ;
    int i = s - b * NOBJ;

    __shared__ float sl[NPAR][NOBJ];
    {
        size_t S = (size_t)NB * NOBJ;
        for (int t = threadIdx.x; t < NPAR * NOBJ; t += 256) {
            int pidx = t / NOBJ, o = t - pidx * NOBJ;
            sl[pidx][o] = par[(size_t)pidx * S + (size_t)b * NOBJ + o];
        }
    }
    __syncthreads();
    int nvb = nv[b];
    if (i >= nvb) return;            // block-uniform; no further barriers below

    float cx = sl[P_CX][i], cy = sl[P_CY][i];
    int wr = (int)sl[P_WR][i], hr = (int)sl[P_HR][i];
    float ivx = sl[P_IVX][i], ivy = sl[P_IVY][i];
    int ci = __float_as_int(sl[P_CLS][i]);
    int xc = (int)cx, yc = (int)cy;
    int xa = max(0, xc - wr), xb = min(WW - 1, xc + wr);
    int ya = max(0, yc - hr), yb = min(HH - 1, yc + hr);
    int wN = xb - xa + 1, hN = yb - ya + 1, npix = wN * hN;

    float posl = 0.f, negl = 0.f, npos = 0.f, wsum = 0.f, gl = 0.f;

    for (int t0 = threadIdx.x; t0 < npix; t0 += 256) {
        int ry = t0 / wN;
        int px = xa + (t0 - ry * wN);
        int py = ya + ry;
        float fx = (float)px, fy = (float)py;

        // first covering object of class ci at this pixel? (ranks [0,nvb) are all valid)
        bool first = true;
        for (int j = 0; j < i; ++j) {
            if (__float_as_int(sl[P_CLS][j]) != ci) continue;
            float dxj = fx - sl[P_CX][j], dyj = fy - sl[P_CY][j];
            if (fabsf(dxj) <= sl[P_WR][j] && fabsf(dyj) <= sl[P_HR][j]) { first = false; break; }
        }

        float dxi = fx - cx, dyi = fy - cy;
        float gi = __expf(-(dxi*dxi) * ivx) * __expf(-(dyi*dyi) * ivy);
        float t = gi;
        bool is_owner = true;        // owner = largest covering sorted idx
        for (int j = i + 1; j < nvb; ++j) {
            float dxj = fx - sl[P_CX][j], dyj = fy - sl[P_CY][j];
            if (fabsf(dxj) <= sl[P_WR][j] && fabsf(dyj) <= sl[P_HR][j]) {
                is_owner = false;
                if (first && __float_as_int(sl[P_CLS][j]) == ci) {
                    float gj = __expf(-(dxj*dxj) * sl[P_IVX][j]) * __expf(-(dyj*dyj) * sl[P_IVY][j]);
                    t = fmaxf(t, gj);
                }
            }
        }

        if (first) {
            // correction vs. dense tgt=0 baseline for (pixel, class ci)
            float h = heat[((size_t)b * NC + ci) * HW + (size_t)py * WW + px];
            float e = __expf(-h);
            float q = 1.f + e;
            float lq = __logf(q);
            float p = 1.f / q;
            float basef = (h + lq) * p * p;
            if (t == 1.0f) {
                posl += lq * (1.f - p) * (1.f - p);   // -log(pred)*(1-pred)^2
                negl -= basef;
                npos += 1.f;
            } else {
                float u1 = 1.f - t;
                float u2 = u1 * u1;
                negl += basef * (u2 * u2 - 1.f);      // weight (1-t)^4 instead of 1
            }
        }

        if (is_owner) {
            float w = gi * sl[P_IVG][i];
            size_t po = (size_t)py * WW + px;
            const float* whb = wh + (size_t)b * 4 * HW + po;
            float w0 = whb[0], w1 = whb[HW], w2 = whb[2*HW], w3 = whb[3*HW];
            float bx = fx * 4.f, by = fy * 4.f;
            float px1 = bx - w0, py1 = by - w1, px2 = bx + w2, py2 = by + w3;
            float tx1 = sl[P_X1][i], ty1 = sl[P_Y1][i];
            float tx2 = sl[P_X2][i], ty2 = sl[P_Y2][i];
            float ltx = fmaxf(px1, tx1), lty = fmaxf(py1, ty1);
            float rbx = fminf(px2, tx2), rby = fminf(py2, ty2);
            float iw = fmaxf(rbx - ltx + 1.f, 0.f), ih = fmaxf(rby - lty + 1.f, 0.f);
            float e1x = fminf(px1, tx1), e1y = fminf(py1, ty1);
            float e2x = fmaxf(px2, tx2), e2y = fmaxf(py2, ty2);
            float ew = fmaxf(e2x - e1x + 1.f, 0.f), eh = fmaxf(e2y - e1y + 1.f, 0.f);
            float ov = iw * ih;
            float ap = (px2 - px1 + 1.f) * (py2 - py1 + 1.f);
            float ag = (tx2 - tx1 + 1.f) * (ty2 - ty1 + 1.f);
            float u = ap + ag - ov;
            float iou = ov / u;
            float ea = ew * eh;
            float giou = iou - (ea - u) / ea;
            wsum += w;
            gl += (1.f - giou) * w;
        }
    }

    // reduce 5 values over 4 waves -> 5 atomics into per-image slots
    float vals[5] = { posl, negl, npos, wsum, gl };
    #pragma unroll
    for (int k = 0; k < 5; ++k) {
        float v = vals[k];
        for (int off = 32; off > 0; off >>= 1) v += __shfl_down(v, off, 64);
        vals[k] = v;
    }
    __shared__ float red[5][4];
    int lane = threadIdx.x & 63, wv = threadIdx.x >> 6;
    if (lane == 0) {
        #pragma unroll
        for (int k = 0; k < 5; ++k) red[k][wv] = vals[k];
    }
    __syncthreads();
    if (threadIdx.x == 0) {
        #pragma unroll
        for (int k = 0; k < 5; ++k) {
            double vsum = (double)red[k][0] + (double)red[k][1] + (double)red[k][2] + (double)red[k][3];
            atomicAdd(&acc[k * 16 + b], vsum);
        }
    }
}

// ---------------- Kernel 3: finalize ----------
__global__ void finalize_kernel(const double* __restrict__ acc, float* __restrict__ out) {
    double posl=0, negc=0, npos=0, wsum=0, gl=0, dneg=0;
    for (int b = 0; b < NB; ++b) {
        posl += acc[0*16 + b];
        negc += acc[1*16 + b];
        npos += acc[2*16 + b];
        wsum += acc[3*16 + b];
        gl   += acc[4*16 + b];
        dneg += acc[80 + b];
    }
    double neg = negc + dneg;
    double hm = (npos > 0.0) ? (posl + neg) / npos : neg;
    out[0] = (float)hm;                               // HM_W = 1.0
    out[1] = (float)(gl / (wsum + 1e-4) * 0.1);       // WH_W = 0.1
}

extern "C" void kernel_launch(void* const* d_in, const int* in_sizes, int n_in,
                              void* d_out, int out_size, void* d_ws, size_t ws_size,
                              hipStream_t stream) {
    const float* heat = (const float*)d_in[0];   // (16,80,128,128)
    const float* wh   = (const float*)d_in[1];   // (16,4,128,128)
    const float* ann  = (const float*)d_in[2];   // (16,100,5)
    float* out = (float*)d_out;

    double* acc = (double*)d_ws;
    int*    nv  = (int*)((char*)d_ws + NV_OFF);
    float*  par = (float*)((char*)d_ws + PAR_OFF);

    prep_kernel<<<NB, 128, 0, stream>>>(ann, acc, nv, par);
    main_kernel<<<TOTAL_BLOCKS, 256, 0, stream>>>(heat, wh, par, nv, acc);
    finalize_kernel<<<1, 1, 0, stream>>>(acc, out);
}

// Round 4
// 141.163 us; speedup vs baseline: 1.5856x; 1.0366x over previous
//
#include <hip/hip_runtime.h>
#include <math.h>

#define NB 16
#define NC 80
#define HH 128
#define WW 128
#define NOBJ 100
#define HW (HH*WW)
#define SCATTER_BLOCKS (NB*NOBJ)                  // 1600, dispatched FIRST
#define F4_TOTAL (NB*NC*HW/4)                     // 5,242,880 float4s
#define F4_PER_BLOCK (256*8)                      // 2048
#define DENSE_BLOCKS (F4_TOTAL/F4_PER_BLOCK)      // 2560
#define TOTAL_BLOCKS (SCATTER_BLOCKS + DENSE_BLOCKS)
#define DENSE_SLOTS 64

// ws layout:
//  [0, 640):     double acc[80]   sparse sums, index k*16+b, k: 0=posl 1=negl_corr 2=npos 3=wsum 4=giou
//  [640, 1152):  double dacc[64]  dense negl partial slots (acc[80..144))
//  [1152, 1216): int nv[NB]
//  [1216, ...):  float4 par[NB*NOBJ*3]  packed per sorted rank:
//                  [0]=(cx,cy,wr,hr) [1]=(ivx,ivy,cls_bits,ivg) [2]=(x1,y1,x2,y2)
#define NV_OFF 1152
#define PAR_OFF 1216

// ---------------- Kernel 1: per-image prep (sort + params + gsum) + zero accumulators ----------
__global__ __launch_bounds__(128) void prep_kernel(const float* __restrict__ ann,
                                                   double* __restrict__ acc,
                                                   int* __restrict__ nv,
                                                   float4* __restrict__ par) {
    int b = blockIdx.x;
    int i = threadIdx.x;
    __shared__ float skey[128];
    __shared__ int s_nv;
    if (i == 0) s_nv = 0;

    // zero this image's accumulator slots (5 sparse + 4 dense slots)
    if (i < 5) acc[i * 16 + b] = 0.0;
    if (i >= 8 && i < 12) acc[80 + b * 4 + (i - 8)] = 0.0;

    float x1=0.f, y1=0.f, x2=0.f, y2=0.f, clsv=-1.f;
    float key = INFINITY;            // key = -log_a; invalid -> +inf (sorted last, stable)
    if (i < NOBJ) {
        const float* a = ann + ((size_t)b * NOBJ + i) * 5;
        x1=a[0]; y1=a[1]; x2=a[2]; y2=a[3]; clsv=a[4];
        if (clsv >= 0.f) {
            float area = (y2 - y1 + 1.f) * (x2 - x1 + 1.f);
            key = -__logf(fmaxf(area, 1e-12f));
        }
    }
    skey[i] = key;
    __syncthreads();

    if (i < NOBJ) {
        // stable ascending rank == jnp.argsort(-log_a)
        int r = 0;
        for (int j = 0; j < NOBJ; ++j) {
            float kj = skey[j];
            if (kj < key || (kj == key && j < i)) r++;
        }
        bool valid = (clsv >= 0.f);
        if (valid) atomicAdd(&s_nv, 1);

        float cx = truncf((x1 + x2) * 0.125f);       // *0.5/DOWN, DOWN=4
        float cy = truncf((y1 + y2) * 0.125f);
        float fx1 = fminf(fmaxf(x1*0.25f, 0.f), WW - 1.f);
        float fx2 = fminf(fmaxf(x2*0.25f, 0.f), WW - 1.f);
        float fy1 = fminf(fmaxf(y1*0.25f, 0.f), HH - 1.f);
        float fy2 = fminf(fmaxf(y2*0.25f, 0.f), HH - 1.f);
        int hr = (int)((fy2 - fy1) * 0.5f * 0.54f);  // trunc matches astype(int32)
        int wr = (int)((fx2 - fx1) * 0.5f * 0.54f);
        float sx = (float)(2*wr + 1) / 6.0f;
        float sy = (float)(2*hr + 1) / 6.0f;
        float ivx = 1.f / (2.f * sx * sx);
        float ivy = 1.f / (2.f * sy * sy);

        // separable gaussian sum (gx carries the valid mask, as in reference)
        int yc = (int)cy, xc = (int)cx;
        float sgy = 0.f;
        {
            int ya = max(0, yc - hr), yb = min(HH - 1, yc + hr);
            for (int y = ya; y <= yb; ++y) {
                float dy = (float)y - cy;
                sgy += __expf(-(dy*dy) * ivy);
            }
        }
        float sgx = 0.f;
        if (valid) {
            int xa = max(0, xc - wr), xb = min(WW - 1, xc + wr);
            for (int x = xa; x <= xb; ++x) {
                float dx = (float)x - cx;
                sgx += __expf(-(dx*dx) * ivx);
            }
        }
        float gsum = fmaxf(sgy * sgx, 1e-12f);
        int cls_i = min(max((int)clsv, 0), NC - 1);

        size_t o = ((size_t)b * NOBJ + (size_t)r) * 3;
        par[o + 0] = make_float4(cx, cy, (float)wr, (float)hr);
        par[o + 1] = make_float4(ivx, ivy, __int_as_float(cls_i), 1.f / gsum);
        par[o + 2] = make_float4(x1, y1, x2, y2);
    }
    __syncthreads();
    if (i == 0) nv[b] = s_nv;
}

// ---------------- Kernel 2: fused scatter (first) + dense focal baseline ----------
__global__ __launch_bounds__(256) void main_kernel(const float* __restrict__ heat,
                                                   const float* __restrict__ wh,
                                                   const float4* __restrict__ par,
                                                   const int* __restrict__ nv,
                                                   double* __restrict__ acc) {
    if (blockIdx.x >= SCATTER_BLOCKS) {
        // ===== dense path: flat streaming focal baseline (tgt = 0) =====
        int db = blockIdx.x - SCATTER_BLOCKS;
        const float4* hp = (const float4*)heat;
        size_t base = (size_t)db * F4_PER_BLOCK + threadIdx.x;
        float4 v[8];
        #pragma unroll
        for (int k = 0; k < 8; ++k) v[k] = hp[base + (size_t)k * 256];
        float n0 = 0.f, n1 = 0.f;
        #pragma unroll
        for (int k = 0; k < 8; ++k) {
            float hv[4] = { v[k].x, v[k].y, v[k].z, v[k].w };
            #pragma unroll
            for (int m = 0; m < 4; ++m) {
                float h = hv[m];
                float e = __expf(-h);
                float q = 1.f + e;
                float lq = __logf(q);
                float p = 1.f / q;
                float t = (h + lq) * p * p;   // -log(1-pred) * pred^2
                if (m & 1) n1 += t; else n0 += t;
            }
        }
        float r = n0 + n1;
        for (int off = 32; off > 0; off >>= 1) r += __shfl_down(r, off, 64);
        __shared__ float dred[4];
        int lane = threadIdx.x & 63, wv = threadIdx.x >> 6;
        if (lane == 0) dred[wv] = r;
        __syncthreads();
        if (threadIdx.x == 0) {
            double s = (double)dred[0] + (double)dred[1] + (double)dred[2] + (double)dred[3];
            atomicAdd(&acc[80 + (db & (DENSE_SLOTS - 1))], s);
        }
        return;
    }

    // ===== scatter path: one block per (image, sorted object), dispatched first =====
    int s = blockIdx.x;
    int b = s / NOBJ;
    int i = s - b * NOBJ;
    int nvb = nv[b];
    if (i >= nvb) return;            // block-uniform, before any barrier

    __shared__ float4 sobj[NOBJ][3];
    {
        const float4* src = par + (size_t)b * NOBJ * 3;
        float4* dst = &sobj[0][0];
        for (int t = threadIdx.x; t < NOBJ * 3; t += 256) dst[t] = src[t];
    }
    __syncthreads();

    float4 g0i = sobj[i][0], g1i = sobj[i][1], g2i = sobj[i][2];
    float cx = g0i.x, cy = g0i.y;
    int wr = (int)g0i.z, hr = (int)g0i.w;
    float ivx = g1i.x, ivy = g1i.y;
    int ci = __float_as_int(g1i.z);
    float ivg = g1i.w;
    int xc = (int)cx, yc = (int)cy;
    int xa = max(0, xc - wr), xb = min(WW - 1, xc + wr);
    int ya = max(0, yc - hr), yb = min(HH - 1, yc + hr);
    int wN = xb - xa + 1, hN = yb - ya + 1, npix = wN * hN;

    float posl = 0.f, negl = 0.f, npos = 0.f, wsum = 0.f, gl = 0.f;

    for (int t0 = threadIdx.x; t0 < npix; t0 += 256) {
        int ry = t0 / wN;
        int px = xa + (t0 - ry * wN);
        int py = ya + ry;
        float fx = (float)px, fy = (float)py;

        // first covering object of class ci at this pixel? (ranks [0,nvb) all valid)
        bool first = true;
        for (int j = 0; j < i; ++j) {
            float4 g1 = sobj[j][1];
            if (__float_as_int(g1.z) != ci) continue;
            float4 g0 = sobj[j][0];
            if (fabsf(fx - g0.x) <= g0.z && fabsf(fy - g0.y) <= g0.w) { first = false; break; }
        }

        float dxi = fx - cx, dyi = fy - cy;
        float gi = __expf(-(dxi*dxi) * ivx) * __expf(-(dyi*dyi) * ivy);
        float t = gi;
        bool is_owner = true;        // owner = largest covering sorted idx
        for (int j = i + 1; j < nvb; ++j) {
            float4 g0 = sobj[j][0];
            float dxj = fx - g0.x, dyj = fy - g0.y;
            if (fabsf(dxj) <= g0.z && fabsf(dyj) <= g0.w) {
                is_owner = false;
                if (first) {
                    float4 g1 = sobj[j][1];
                    if (__float_as_int(g1.z) == ci) {
                        float gj = __expf(-(dxj*dxj) * g1.x) * __expf(-(dyj*dyj) * g1.y);
                        t = fmaxf(t, gj);
                    }
                }
            }
        }

        if (first) {
            // correction vs. dense tgt=0 baseline for (pixel, class ci)
            float h = heat[((size_t)b * NC + ci) * HW + (size_t)py * WW + px];
            float e = __expf(-h);
            float q = 1.f + e;
            float lq = __logf(q);
            float p = 1.f / q;
            float basef = (h + lq) * p * p;
            if (t == 1.0f) {
                posl += lq * (1.f - p) * (1.f - p);   // -log(pred)*(1-pred)^2
                negl -= basef;
                npos += 1.f;
            } else {
                float u1 = 1.f - t;
                float u2 = u1 * u1;
                negl += basef * (u2 * u2 - 1.f);      // weight (1-t)^4 instead of 1
            }
        }

        if (is_owner) {
            float w = gi * ivg;
            size_t po = (size_t)py * WW + px;
            const float* whb = wh + (size_t)b * 4 * HW + po;
            float w0 = whb[0], w1 = whb[HW], w2 = whb[2*HW], w3 = whb[3*HW];
            float bx = fx * 4.f, by = fy * 4.f;
            float px1 = bx - w0, py1 = by - w1, px2 = bx + w2, py2 = by + w3;
            float tx1 = g2i.x, ty1 = g2i.y, tx2 = g2i.z, ty2 = g2i.w;
            float ltx = fmaxf(px1, tx1), lty = fmaxf(py1, ty1);
            float rbx = fminf(px2, tx2), rby = fminf(py2, ty2);
            float iw = fmaxf(rbx - ltx + 1.f, 0.f), ih = fmaxf(rby - lty + 1.f, 0.f);
            float e1x = fminf(px1, tx1), e1y = fminf(py1, ty1);
            float e2x = fmaxf(px2, tx2), e2y = fmaxf(py2, ty2);
            float ew = fmaxf(e2x - e1x + 1.f, 0.f), eh = fmaxf(e2y - e1y + 1.f, 0.f);
            float ov = iw * ih;
            float ap = (px2 - px1 + 1.f) * (py2 - py1 + 1.f);
            float ag = (tx2 - tx1 + 1.f) * (ty2 - ty1 + 1.f);
            float u = ap + ag - ov;
            float iou = ov / u;
            float ea = ew * eh;
            float giou = iou - (ea - u) / ea;
            wsum += w;
            gl += (1.f - giou) * w;
        }
    }

    // reduce 5 values over 4 waves -> 5 atomics into per-image slots
    float vals[5] = { posl, negl, npos, wsum, gl };
    #pragma unroll
    for (int k = 0; k < 5; ++k) {
        float v = vals[k];
        for (int off = 32; off > 0; off >>= 1) v += __shfl_down(v, off, 64);
        vals[k] = v;
    }
    __shared__ float red[5][4];
    int lane = threadIdx.x & 63, wv = threadIdx.x >> 6;
    if (lane == 0) {
        #pragma unroll
        for (int k = 0; k < 5; ++k) red[k][wv] = vals[k];
    }
    __syncthreads();
    if (threadIdx.x == 0) {
        #pragma unroll
        for (int k = 0; k < 5; ++k) {
            double vsum = (double)red[k][0] + (double)red[k][1] + (double)red[k][2] + (double)red[k][3];
            atomicAdd(&acc[k * 16 + b], vsum);
        }
    }
}

// ---------------- Kernel 3: finalize ----------
__global__ void finalize_kernel(const double* __restrict__ acc, float* __restrict__ out) {
    double posl=0, negc=0, npos=0, wsum=0, gl=0, dneg=0;
    for (int b = 0; b < NB; ++b) {
        posl += acc[0*16 + b];
        negc += acc[1*16 + b];
        npos += acc[2*16 + b];
        wsum += acc[3*16 + b];
        gl   += acc[4*16 + b];
    }
    for (int k = 0; k < DENSE_SLOTS; ++k) dneg += acc[80 + k];
    double neg = negc + dneg;
    double hm = (npos > 0.0) ? (posl + neg) / npos : neg;
    out[0] = (float)hm;                               // HM_W = 1.0
    out[1] = (float)(gl / (wsum + 1e-4) * 0.1);       // WH_W = 0.1
}

extern "C" void kernel_launch(void* const* d_in, const int* in_sizes, int n_in,
                              void* d_out, int out_size, void* d_ws, size_t ws_size,
                              hipStream_t stream) {
    const float* heat = (const float*)d_in[0];   // (16,80,128,128)
    const float* wh   = (const float*)d_in[1];   // (16,4,128,128)
    const float* ann  = (const float*)d_in[2];   // (16,100,5)
    float* out = (float*)d_out;

    double* acc = (double*)d_ws;
    int*    nv  = (int*)((char*)d_ws + NV_OFF);
    float4* par = (float4*)((char*)d_ws + PAR_OFF);

    prep_kernel<<<NB, 128, 0, stream>>>(ann, acc, nv, par);
    main_kernel<<<TOTAL_BLOCKS, 256, 0, stream>>>(heat, wh, par, nv, acc);
    finalize_kernel<<<1, 1, 0, stream>>>(acc, out);
}

// Round 5
// 136.447 us; speedup vs baseline: 1.6404x; 1.0346x over previous
//
#include <hip/hip_runtime.h>
#include <math.h>

#define NB 16
#define NC 80
#define HH 128
#define WW 128
#define NOBJ 100
#define HW (HH*WW)
#define SCATTER_BLOCKS (NB*NOBJ)                  // 1600, dispatched FIRST
#define F4_TOTAL (NB*NC*HW/4)                     // 5,242,880 float4s
#define F4_PER_BLOCK (256*8)                      // 2048
#define DENSE_BLOCKS (F4_TOTAL/F4_PER_BLOCK)      // 2560
#define TOTAL_BLOCKS (SCATTER_BLOCKS + DENSE_BLOCKS)

// ws layout (doubles, every slot written every launch -> poison-safe, no memset):
//  part[0 .. DENSE_BLOCKS)                      dense negl partial per dense block
//  part[DENSE_BLOCKS + s*5 + k], k=0..4         scatter partials: posl, negl_corr, npos, wsum, giou
#define SACC_OFF DENSE_BLOCKS

// ---------------- Kernel 1: fused scatter (first) + dense focal baseline ----------
__global__ __launch_bounds__(256, 4) void main_kernel(const float* __restrict__ heat,
                                                      const float* __restrict__ wh,
                                                      const float* __restrict__ ann,
                                                      double* __restrict__ part) {
    if (blockIdx.x >= SCATTER_BLOCKS) {
        // ===== dense path: flat streaming focal baseline (tgt = 0) =====
        int db = blockIdx.x - SCATTER_BLOCKS;
        const float4* hp = (const float4*)heat;
        size_t base = (size_t)db * F4_PER_BLOCK + threadIdx.x;
        float4 v[8];
        #pragma unroll
        for (int k = 0; k < 8; ++k) v[k] = hp[base + (size_t)k * 256];
        float n0 = 0.f, n1 = 0.f;
        #pragma unroll
        for (int k = 0; k < 8; ++k) {
            float hv[4] = { v[k].x, v[k].y, v[k].z, v[k].w };
            #pragma unroll
            for (int m = 0; m < 4; ++m) {
                float h = hv[m];
                float e = __expf(-h);
                float q = 1.f + e;
                float lq = __logf(q);
                float p = 1.f / q;
                float t = (h + lq) * p * p;     // -log(1-pred) * pred^2
                if (m & 1) n1 += t; else n0 += t;
            }
        }
        float r = n0 + n1;
        for (int off = 32; off > 0; off >>= 1) r += __shfl_down(r, off, 64);
        __shared__ float dred[4];
        int lane = threadIdx.x & 63, wv = threadIdx.x >> 6;
        if (lane == 0) dred[wv] = r;
        __syncthreads();
        if (threadIdx.x == 0)
            part[db] = (double)dred[0] + (double)dred[1] + (double)dred[2] + (double)dred[3];
        return;
    }

    // ===== scatter path: one block per (image, sorted object), self-contained prep =====
    int sblk = blockIdx.x;
    int b = sblk / NOBJ;
    int i = sblk - b * NOBJ;
    double* sacc = part + SACC_OFF + (size_t)sblk * 5;
    int tid = threadIdx.x;

    __shared__ float4 sg0[NOBJ];   // cx, cy, wr, hr
    __shared__ float4 sg1[NOBJ];   // ivx, ivy, cls_bits, ivg
    __shared__ float4 sg2[NOBJ];   // x1, y1, x2, y2
    __shared__ float skey[NOBJ];
    __shared__ int prevl[NOBJ], nextl[NOBJ];
    __shared__ int s_nv, s_np, s_nn;
    if (tid == 0) { s_nv = 0; s_np = 0; s_nn = 0; }

    // ---- phase A: sort + per-object params + gsum (all in LDS, no global round-trip)
    float x1=0.f, y1=0.f, x2=0.f, y2=0.f, clsv=-1.f;
    float key = INFINITY;            // key = -log_a; invalid -> +inf (sorted last, stable)
    bool on = tid < NOBJ;
    if (on) {
        const float* a = ann + ((size_t)b * NOBJ + tid) * 5;
        x1=a[0]; y1=a[1]; x2=a[2]; y2=a[3]; clsv=a[4];
        if (clsv >= 0.f) {
            float area = (y2 - y1 + 1.f) * (x2 - x1 + 1.f);
            key = -__logf(fmaxf(area, 1e-12f));
        }
        skey[tid] = key;
    }
    __syncthreads();

    if (on) {
        // stable ascending rank == jnp.argsort(-log_a)
        int r = 0;
        for (int j = 0; j < NOBJ; ++j) {
            float kj = skey[j];
            if (kj < key || (kj == key && j < tid)) r++;
        }
        bool valid = (clsv >= 0.f);
        if (valid) atomicAdd(&s_nv, 1);

        float cx = truncf((x1 + x2) * 0.125f);       // *0.5/DOWN, DOWN=4
        float cy = truncf((y1 + y2) * 0.125f);
        float fx1 = fminf(fmaxf(x1*0.25f, 0.f), WW - 1.f);
        float fx2 = fminf(fmaxf(x2*0.25f, 0.f), WW - 1.f);
        float fy1 = fminf(fmaxf(y1*0.25f, 0.f), HH - 1.f);
        float fy2 = fminf(fmaxf(y2*0.25f, 0.f), HH - 1.f);
        int hr = (int)((fy2 - fy1) * 0.5f * 0.54f);  // trunc matches astype(int32)
        int wr = (int)((fx2 - fx1) * 0.5f * 0.54f);
        float sx = (float)(2*wr + 1) / 6.0f;
        float sy = (float)(2*hr + 1) / 6.0f;
        float ivx = 1.f / (2.f * sx * sx);
        float ivy = 1.f / (2.f * sy * sy);

        // separable gaussian sum (gx carries the valid mask, as in reference)
        int yc = (int)cy, xc = (int)cx;
        float sgy = 0.f;
        {
            int ya = max(0, yc - hr), yb = min(HH - 1, yc + hr);
            for (int y = ya; y <= yb; ++y) {
                float dy = (float)y - cy;
                sgy += __expf(-(dy*dy) * ivy);
            }
        }
        float sgx = 0.f;
        if (valid) {
            int xa = max(0, xc - wr), xb = min(WW - 1, xc + wr);
            for (int x = xa; x <= xb; ++x) {
                float dx = (float)x - cx;
                sgx += __expf(-(dx*dx) * ivx);
            }
        }
        float gsum = fmaxf(sgy * sgx, 1e-12f);
        int cls_i = min(max((int)clsv, 0), NC - 1);

        sg0[r] = make_float4(cx, cy, (float)wr, (float)hr);
        sg1[r] = make_float4(ivx, ivy, __int_as_float(cls_i), 1.f / gsum);
        sg2[r] = make_float4(x1, y1, x2, y2);
    }
    __syncthreads();

    int nvb = s_nv;
    if (i >= nvb) {                  // block-uniform; all barriers already passed
        if (tid < 5) sacc[tid] = 0.0;
        return;
    }

    float4 g0i = sg0[i], g1i = sg1[i], g2i = sg2[i];
    float cx = g0i.x, cy = g0i.y;
    int wr = (int)g0i.z, hr = (int)g0i.w;
    float ivx = g1i.x, ivy = g1i.y;
    int ci = __float_as_int(g1i.z);
    float ivg = g1i.w;
    int xc = (int)cx, yc = (int)cy;
    int xa = max(0, xc - wr), xb = min(WW - 1, xc + wr);
    int ya = max(0, yc - hr), yb = min(HH - 1, yc + hr);
    int wN = xb - xa + 1, hN = yb - ya + 1, npix = wN * hN;

    // ---- candidate lists: objects whose (unclipped) window intersects mine ----
    if (tid < nvb && tid != i) {
        float4 g0 = sg0[tid];
        bool inter = (g0.x - g0.z <= (float)xb) && (g0.x + g0.z >= (float)xa) &&
                     (g0.y - g0.w <= (float)yb) && (g0.y + g0.w >= (float)ya);
        if (inter) {
            int cj = __float_as_int(sg1[tid].z);
            if (tid < i) {
                if (cj == ci) prevl[atomicAdd(&s_np, 1)] = tid;
            } else {
                nextl[atomicAdd(&s_nn, 1)] = tid | ((cj == ci) ? 0x10000 : 0);
            }
        }
    }
    __syncthreads();
    int np = s_np, nn = s_nn;

    float posl = 0.f, negl = 0.f, npos = 0.f, wsum = 0.f, gl = 0.f;

    for (int t0 = tid; t0 < npix; t0 += 256) {   // npix <= 225 here: single iteration
        int ry = t0 / wN;
        int px = xa + (t0 - ry * wN);
        int py = ya + ry;
        float fx = (float)px, fy = (float)py;

        // first covering object of class ci at this pixel? (order-free existence)
        bool first = true;
        for (int k = 0; k < np; ++k) {
            float4 g0 = sg0[prevl[k]];
            if (fabsf(fx - g0.x) <= g0.z && fabsf(fy - g0.y) <= g0.w) first = false;
        }

        float dxi = fx - cx, dyi = fy - cy;
        float gi = __expf(-(dxi*dxi) * ivx) * __expf(-(dyi*dyi) * ivy);
        float t = gi;
        bool is_owner = true;        // owner = largest covering sorted idx
        for (int k = 0; k < nn; ++k) {
            int e = nextl[k];
            int j = e & 0xFFFF;
            float4 g0 = sg0[j];
            float dxj = fx - g0.x, dyj = fy - g0.y;
            if (fabsf(dxj) <= g0.z && fabsf(dyj) <= g0.w) {
                is_owner = false;
                if ((e & 0x10000) && first) {
                    float4 g1 = sg1[j];
                    float gj = __expf(-(dxj*dxj) * g1.x) * __expf(-(dyj*dyj) * g1.y);
                    t = fmaxf(t, gj);
                }
            }
        }

        if (first) {
            // correction vs. dense tgt=0 baseline for (pixel, class ci)
            float h = heat[((size_t)b * NC + ci) * HW + (size_t)py * WW + px];
            float e = __expf(-h);
            float q = 1.f + e;
            float lq = __logf(q);
            float p = 1.f / q;
            float basef = (h + lq) * p * p;
            if (t == 1.0f) {
                posl += lq * (1.f - p) * (1.f - p);   // -log(pred)*(1-pred)^2
                negl -= basef;
                npos += 1.f;
            } else {
                float u1 = 1.f - t;
                float u2 = u1 * u1;
                negl += basef * (u2 * u2 - 1.f);      // weight (1-t)^4 instead of 1
            }
        }

        if (is_owner) {
            float w = gi * ivg;
            size_t po = (size_t)py * WW + px;
            const float* whb = wh + (size_t)b * 4 * HW + po;
            float w0 = whb[0], w1 = whb[HW], w2 = whb[2*HW], w3 = whb[3*HW];
            float bx = fx * 4.f, by = fy * 4.f;
            float px1 = bx - w0, py1 = by - w1, px2 = bx + w2, py2 = by + w3;
            float tx1 = g2i.x, ty1 = g2i.y, tx2 = g2i.z, ty2 = g2i.w;
            float ltx = fmaxf(px1, tx1), lty = fmaxf(py1, ty1);
            float rbx = fminf(px2, tx2), rby = fminf(py2, ty2);
            float iw = fmaxf(rbx - ltx + 1.f, 0.f), ih = fmaxf(rby - lty + 1.f, 0.f);
            float e1x = fminf(px1, tx1), e1y = fminf(py1, ty1);
            float e2x = fmaxf(px2, tx2), e2y = fmaxf(py2, ty2);
            float ew = fmaxf(e2x - e1x + 1.f, 0.f), eh = fmaxf(e2y - e1y + 1.f, 0.f);
            float ov = iw * ih;
            float ap = (px2 - px1 + 1.f) * (py2 - py1 + 1.f);
            float ag = (tx2 - tx1 + 1.f) * (ty2 - ty1 + 1.f);
            float u = ap + ag - ov;
            float iou = ov / u;
            float ea = ew * eh;
            float giou = iou - (ea - u) / ea;
            wsum += w;
            gl += (1.f - giou) * w;
        }
    }

    // reduce 5 values over 4 waves -> plain stores to this block's unique slot
    float vals[5] = { posl, negl, npos, wsum, gl };
    #pragma unroll
    for (int k = 0; k < 5; ++k) {
        float v = vals[k];
        for (int off = 32; off > 0; off >>= 1) v += __shfl_down(v, off, 64);
        vals[k] = v;
    }
    __shared__ float red[5][4];
    int lane = tid & 63, wv = tid >> 6;
    if (lane == 0) {
        #pragma unroll
        for (int k = 0; k < 5; ++k) red[k][wv] = vals[k];
    }
    __syncthreads();
    if (tid == 0) {
        #pragma unroll
        for (int k = 0; k < 5; ++k)
            sacc[k] = (double)red[k][0] + (double)red[k][1] + (double)red[k][2] + (double)red[k][3];
    }
}

// ---------------- Kernel 2: finalize (parallel reduction over all partials) ----------
__global__ __launch_bounds__(256) void finalize_kernel(const double* __restrict__ part,
                                                       float* __restrict__ out) {
    int tid = threadIdx.x;
    double v[6] = {0,0,0,0,0,0};     // dneg, posl, negc, npos, wsum, gl
    for (int d = tid; d < DENSE_BLOCKS; d += 256) v[0] += part[d];
    for (int s = tid; s < SCATTER_BLOCKS; s += 256) {
        const double* p = part + SACC_OFF + (size_t)s * 5;
        v[1] += p[0]; v[2] += p[1]; v[3] += p[2]; v[4] += p[3]; v[5] += p[4];
    }
    #pragma unroll
    for (int k = 0; k < 6; ++k) {
        double x = v[k];
        for (int off = 32; off > 0; off >>= 1) x += __shfl_down(x, off, 64);
        v[k] = x;
    }
    __shared__ double red[6][4];
    int lane = tid & 63, wv = tid >> 6;
    if (lane == 0) {
        #pragma unroll
        for (int k = 0; k < 6; ++k) red[k][wv] = v[k];
    }
    __syncthreads();
    if (tid == 0) {
        double dneg = red[0][0] + red[0][1] + red[0][2] + red[0][3];
        double posl = red[1][0] + red[1][1] + red[1][2] + red[1][3];
        double negc = red[2][0] + red[2][1] + red[2][2] + red[2][3];
        double npos = red[3][0] + red[3][1] + red[3][2] + red[3][3];
        double wsum = red[4][0] + red[4][1] + red[4][2] + red[4][3];
        double gl   = red[5][0] + red[5][1] + red[5][2] + red[5][3];
        double neg = negc + dneg;
        double hm = (npos > 0.0) ? (posl + neg) / npos : neg;
        out[0] = (float)hm;                           // HM_W = 1.0
        out[1] = (float)(gl / (wsum + 1e-4) * 0.1);   // WH_W = 0.1
    }
}

extern "C" void kernel_launch(void* const* d_in, const int* in_sizes, int n_in,
                              void* d_out, int out_size, void* d_ws, size_t ws_size,
                              hipStream_t stream) {
    const float* heat = (const float*)d_in[0];   // (16,80,128,128)
    const float* wh   = (const float*)d_in[1];   // (16,4,128,128)
    const float* ann  = (const float*)d_in[2];   // (16,100,5)
    float* out = (float*)d_out;

    double* part = (double*)d_ws;

    main_kernel<<<TOTAL_BLOCKS, 256, 0, stream>>>(heat, wh, ann, part);
    finalize_kernel<<<1, 256, 0, stream>>>(part, out);
}

// Round 6
// 131.387 us; speedup vs baseline: 1.7035x; 1.0385x over previous
//
#include <hip/hip_runtime.h>
#include <math.h>

#define NB 16
#define NC 80
#define HH 128
#define WW 128
#define NOBJ 100
#define HW (HH*WW)
#define SCATTER_BLOCKS (NB*NOBJ)                  // 1600
#define F4_TOTAL (NB*NC*HW/4)                     // 5,242,880 float4s
#define F4_PER_BLOCK (256*8)                      // 2048
#define DENSE_BLOCKS (F4_TOTAL/F4_PER_BLOCK)      // 2560
#define TOTAL_BLOCKS (SCATTER_BLOCKS + DENSE_BLOCKS)   // 4160 = 13*320; 1600/4160 = 5/13

// ws layout (doubles, every slot written every launch -> poison-safe, no memset):
//  part[0 .. DENSE_BLOCKS)                      dense negl partial per dense block
//  part[DENSE_BLOCKS + s*5 + k], k=0..4         scatter partials: posl, negl_corr, npos, wsum, giou
#define SACC_OFF DENSE_BLOCKS

// ---------------- Kernel 1: interleaved scatter + dense focal baseline ----------
__global__ __launch_bounds__(256, 4) void main_kernel(const float* __restrict__ heat,
                                                      const float* __restrict__ wh,
                                                      const float* __restrict__ ann,
                                                      double* __restrict__ part) {
    // interleave: of every 13 consecutive blocks, 5 are scatter, 8 are dense
    int grp = blockIdx.x / 13;
    int rem = blockIdx.x - grp * 13;
    bool is_scatter = rem < 5;

    if (!is_scatter) {
        // ===== dense path: flat streaming focal baseline (tgt = 0) =====
        int db = grp * 8 + (rem - 5);
        const float4* hp = (const float4*)heat;
        size_t base = (size_t)db * F4_PER_BLOCK + threadIdx.x;
        float4 v[8];
        #pragma unroll
        for (int k = 0; k < 8; ++k) v[k] = hp[base + (size_t)k * 256];
        float n0 = 0.f, n1 = 0.f;
        #pragma unroll
        for (int k = 0; k < 8; ++k) {
            float hv[4] = { v[k].x, v[k].y, v[k].z, v[k].w };
            #pragma unroll
            for (int m = 0; m < 4; ++m) {
                float h = hv[m];
                float e = __expf(-h);
                float q = 1.f + e;
                float lq = __logf(q);
                float p = 1.f / q;
                float t = (h + lq) * p * p;     // -log(1-pred) * pred^2
                if (m & 1) n1 += t; else n0 += t;
            }
        }
        float r = n0 + n1;
        for (int off = 32; off > 0; off >>= 1) r += __shfl_down(r, off, 64);
        __shared__ float dred[4];
        int lane = threadIdx.x & 63, wv = threadIdx.x >> 6;
        if (lane == 0) dred[wv] = r;
        __syncthreads();
        if (threadIdx.x == 0)
            part[db] = (double)dred[0] + (double)dred[1] + (double)dred[2] + (double)dred[3];
        return;
    }

    // ===== scatter path: one block per (image, sorted object), self-contained prep =====
    int sblk = grp * 5 + rem;
    int b = sblk / NOBJ;
    int i = sblk - b * NOBJ;
    double* sacc = part + SACC_OFF + (size_t)sblk * 5;
    int tid = threadIdx.x;

    __shared__ float4 sg0[NOBJ];   // cx, cy, wr, hr
    __shared__ float4 sg1[NOBJ];   // ivx, ivy, cls_bits, ivg
    __shared__ float4 sg2[NOBJ];   // x1, y1, x2, y2
    __shared__ float skey[NOBJ];
    __shared__ int prevl[NOBJ], nextl[NOBJ];
    __shared__ int s_nv, s_np, s_nn;
    if (tid == 0) { s_nv = 0; s_np = 0; s_nn = 0; }

    // ---- phase A: sort + per-object params + gsum (all in LDS)
    float x1=0.f, y1=0.f, x2=0.f, y2=0.f, clsv=-1.f;
    float key = INFINITY;            // key = -log_a; invalid -> +inf (sorted last, stable)
    bool on = tid < NOBJ;
    if (on) {
        const float* a = ann + ((size_t)b * NOBJ + tid) * 5;
        x1=a[0]; y1=a[1]; x2=a[2]; y2=a[3]; clsv=a[4];
        if (clsv >= 0.f) {
            float area = (y2 - y1 + 1.f) * (x2 - x1 + 1.f);
            key = -__logf(fmaxf(area, 1e-12f));
        }
        skey[tid] = key;
    }
    __syncthreads();

    if (on) {
        // stable ascending rank == jnp.argsort(-log_a)
        int r = 0;
        for (int j = 0; j < NOBJ; ++j) {
            float kj = skey[j];
            if (kj < key || (kj == key && j < tid)) r++;
        }
        bool valid = (clsv >= 0.f);
        if (valid) atomicAdd(&s_nv, 1);

        float cx = truncf((x1 + x2) * 0.125f);       // *0.5/DOWN, DOWN=4
        float cy = truncf((y1 + y2) * 0.125f);
        float fx1 = fminf(fmaxf(x1*0.25f, 0.f), WW - 1.f);
        float fx2 = fminf(fmaxf(x2*0.25f, 0.f), WW - 1.f);
        float fy1 = fminf(fmaxf(y1*0.25f, 0.f), HH - 1.f);
        float fy2 = fminf(fmaxf(y2*0.25f, 0.f), HH - 1.f);
        int hr = (int)((fy2 - fy1) * 0.5f * 0.54f);  // trunc matches astype(int32)
        int wr = (int)((fx2 - fx1) * 0.5f * 0.54f);
        float sx = (float)(2*wr + 1) / 6.0f;
        float sy = (float)(2*hr + 1) / 6.0f;
        float ivx = 1.f / (2.f * sx * sx);
        float ivy = 1.f / (2.f * sy * sy);

        // separable gaussian sum (gx carries the valid mask, as in reference)
        int yc = (int)cy, xc = (int)cx;
        float sgy = 0.f;
        {
            int ya = max(0, yc - hr), yb = min(HH - 1, yc + hr);
            for (int y = ya; y <= yb; ++y) {
                float dy = (float)y - cy;
                sgy += __expf(-(dy*dy) * ivy);
            }
        }
        float sgx = 0.f;
        if (valid) {
            int xa = max(0, xc - wr), xb = min(WW - 1, xc + wr);
            for (int x = xa; x <= xb; ++x) {
                float dx = (float)x - cx;
                sgx += __expf(-(dx*dx) * ivx);
            }
        }
        float gsum = fmaxf(sgy * sgx, 1e-12f);
        int cls_i = min(max((int)clsv, 0), NC - 1);

        sg0[r] = make_float4(cx, cy, (float)wr, (float)hr);
        sg1[r] = make_float4(ivx, ivy, __int_as_float(cls_i), 1.f / gsum);
        sg2[r] = make_float4(x1, y1, x2, y2);
    }
    __syncthreads();

    int nvb = s_nv;
    if (i >= nvb) {                  // block-uniform; all barriers already passed
        if (tid < 5) sacc[tid] = 0.0;
        return;
    }

    float4 g0i = sg0[i], g1i = sg1[i], g2i = sg2[i];
    float cx = g0i.x, cy = g0i.y;
    int wr = (int)g0i.z, hr = (int)g0i.w;
    float ivx = g1i.x, ivy = g1i.y;
    int ci = __float_as_int(g1i.z);
    float ivg = g1i.w;
    int xc = (int)cx, yc = (int)cy;
    int xa = max(0, xc - wr), xb = min(WW - 1, xc + wr);
    int ya = max(0, yc - hr), yb = min(HH - 1, yc + hr);
    int wN = xb - xa + 1, hN = yb - ya + 1, npix = wN * hN;

    // ---- candidate lists: objects whose (unclipped) window intersects mine ----
    if (tid < nvb && tid != i) {
        float4 g0 = sg0[tid];
        bool inter = (g0.x - g0.z <= (float)xb) && (g0.x + g0.z >= (float)xa) &&
                     (g0.y - g0.w <= (float)yb) && (g0.y + g0.w >= (float)ya);
        if (inter) {
            int cj = __float_as_int(sg1[tid].z);
            if (tid < i) {
                if (cj == ci) prevl[atomicAdd(&s_np, 1)] = tid;
            } else {
                nextl[atomicAdd(&s_nn, 1)] = tid | ((cj == ci) ? 0x10000 : 0);
            }
        }
    }
    __syncthreads();
    int np = s_np, nn = s_nn;

    float posl = 0.f, negl = 0.f, npos = 0.f, wsum = 0.f, gl = 0.f;

    for (int t0 = tid; t0 < npix; t0 += 256) {   // npix <= 225 here: single iteration
        int ry = t0 / wN;
        int px = xa + (t0 - ry * wN);
        int py = ya + ry;
        float fx = (float)px, fy = (float)py;

        // first covering object of class ci at this pixel? (order-free existence)
        bool first = true;
        for (int k = 0; k < np; ++k) {
            float4 g0 = sg0[prevl[k]];
            if (fabsf(fx - g0.x) <= g0.z && fabsf(fy - g0.y) <= g0.w) first = false;
        }

        float dxi = fx - cx, dyi = fy - cy;
        float gi = __expf(-(dxi*dxi) * ivx) * __expf(-(dyi*dyi) * ivy);
        float t = gi;
        bool is_owner = true;        // owner = largest covering sorted idx
        for (int k = 0; k < nn; ++k) {
            int e = nextl[k];
            int j = e & 0xFFFF;
            float4 g0 = sg0[j];
            float dxj = fx - g0.x, dyj = fy - g0.y;
            if (fabsf(dxj) <= g0.z && fabsf(dyj) <= g0.w) {
                is_owner = false;
                if ((e & 0x10000) && first) {
                    float4 g1 = sg1[j];
                    float gj = __expf(-(dxj*dxj) * g1.x) * __expf(-(dyj*dyj) * g1.y);
                    t = fmaxf(t, gj);
                }
            }
        }

        if (first) {
            // correction vs. dense tgt=0 baseline for (pixel, class ci)
            float h = heat[((size_t)b * NC + ci) * HW + (size_t)py * WW + px];
            float e = __expf(-h);
            float q = 1.f + e;
            float lq = __logf(q);
            float p = 1.f / q;
            float basef = (h + lq) * p * p;
            if (t == 1.0f) {
                posl += lq * (1.f - p) * (1.f - p);   // -log(pred)*(1-pred)^2
                negl -= basef;
                npos += 1.f;
            } else {
                float u1 = 1.f - t;
                float u2 = u1 * u1;
                negl += basef * (u2 * u2 - 1.f);      // weight (1-t)^4 instead of 1
            }
        }

        if (is_owner) {
            float w = gi * ivg;
            size_t po = (size_t)py * WW + px;
            const float* whb = wh + (size_t)b * 4 * HW + po;
            float w0 = whb[0], w1 = whb[HW], w2 = whb[2*HW], w3 = whb[3*HW];
            float bx = fx * 4.f, by = fy * 4.f;
            float px1 = bx - w0, py1 = by - w1, px2 = bx + w2, py2 = by + w3;
            float tx1 = g2i.x, ty1 = g2i.y, tx2 = g2i.z, ty2 = g2i.w;
            float ltx = fmaxf(px1, tx1), lty = fmaxf(py1, ty1);
            float rbx = fminf(px2, tx2), rby = fminf(py2, ty2);
            float iw = fmaxf(rbx - ltx + 1.f, 0.f), ih = fmaxf(rby - lty + 1.f, 0.f);
            float e1x = fminf(px1, tx1), e1y = fminf(py1, ty1);
            float e2x = fmaxf(px2, tx2), e2y = fmaxf(py2, ty2);
            float ew = fmaxf(e2x - e1x + 1.f, 0.f), eh = fmaxf(e2y - e1y + 1.f, 0.f);
            float ov = iw * ih;
            float ap = (px2 - px1 + 1.f) * (py2 - py1 + 1.f);
            float ag = (tx2 - tx1 + 1.f) * (ty2 - ty1 + 1.f);
            float u = ap + ag - ov;
            float iou = ov / u;
            float ea = ew * eh;
            float giou = iou - (ea - u) / ea;
            wsum += w;
            gl += (1.f - giou) * w;
        }
    }

    // reduce 5 values over 4 waves -> plain stores to this block's unique slot
    float vals[5] = { posl, negl, npos, wsum, gl };
    #pragma unroll
    for (int k = 0; k < 5; ++k) {
        float v = vals[k];
        for (int off = 32; off > 0; off >>= 1) v += __shfl_down(v, off, 64);
        vals[k] = v;
    }
    __shared__ float red[5][4];
    int lane = tid & 63, wv = tid >> 6;
    if (lane == 0) {
        #pragma unroll
        for (int k = 0; k < 5; ++k) red[k][wv] = vals[k];
    }
    __syncthreads();
    if (tid == 0) {
        #pragma unroll
        for (int k = 0; k < 5; ++k)
            sacc[k] = (double)red[k][0] + (double)red[k][1] + (double)red[k][2] + (double)red[k][3];
    }
}

// ---------------- Kernel 2: finalize (parallel reduction over all partials) ----------
__global__ __launch_bounds__(512) void finalize_kernel(const double* __restrict__ part,
                                                       float* __restrict__ out) {
    int tid = threadIdx.x;
    double v[6] = {0,0,0,0,0,0};     // dneg, posl, negc, npos, wsum, gl
    for (int d = tid; d < DENSE_BLOCKS; d += 512) v[0] += part[d];
    for (int s = tid; s < SCATTER_BLOCKS; s += 512) {
        const double* p = part + SACC_OFF + (size_t)s * 5;
        v[1] += p[0]; v[2] += p[1]; v[3] += p[2]; v[4] += p[3]; v[5] += p[4];
    }
    #pragma unroll
    for (int k = 0; k < 6; ++k) {
        double x = v[k];
        for (int off = 32; off > 0; off >>= 1) x += __shfl_down(x, off, 64);
        v[k] = x;
    }
    __shared__ double red[6][8];
    int lane = tid & 63, wv = tid >> 6;
    if (lane == 0) {
        #pragma unroll
        for (int k = 0; k < 6; ++k) red[k][wv] = v[k];
    }
    __syncthreads();
    if (tid == 0) {
        double s[6];
        #pragma unroll
        for (int k = 0; k < 6; ++k) {
            double x = 0.0;
            for (int w = 0; w < 8; ++w) x += red[k][w];
            s[k] = x;
        }
        double neg = s[2] + s[0];
        double hm = (s[3] > 0.0) ? (s[1] + neg) / s[3] : neg;
        out[0] = (float)hm;                           // HM_W = 1.0
        out[1] = (float)(s[5] / (s[4] + 1e-4) * 0.1); // WH_W = 0.1
    }
}

extern "C" void kernel_launch(void* const* d_in, const int* in_sizes, int n_in,
                              void* d_out, int out_size, void* d_ws, size_t ws_size,
                              hipStream_t stream) {
    const float* heat = (const float*)d_in[0];   // (16,80,128,128)
    const float* wh   = (const float*)d_in[1];   // (16,4,128,128)
    const float* ann  = (const float*)d_in[2];   // (16,100,5)
    float* out = (float*)d_out;

    double* part = (double*)d_ws;

    main_kernel<<<TOTAL_BLOCKS, 256, 0, stream>>>(heat, wh, ann, part);
    finalize_kernel<<<1, 512, 0, stream>>>(part, out);
}